// Round 6
// baseline (294.357 us; speedup 1.0000x reference)
//
#include <hip/hip_runtime.h>
#include <hip/hip_bf16.h>
#include <math.h>

static constexpr int kN   = 50000;   // nodes
static constexpr int kE   = 800000;  // edges
static constexpr int kHID = 256;
static constexpr int kHD  = 32;

typedef short bf16x8 __attribute__((ext_vector_type(8)));
typedef float f32x4  __attribute__((ext_vector_type(4)));
typedef unsigned short us8 __attribute__((ext_vector_type(8)));

__device__ __forceinline__ float b2f(unsigned short u) {
  union { unsigned v; float f; } c; c.v = ((unsigned)u) << 16; return c.f;
}

__device__ __forceinline__ unsigned short f2bu(float f) {
  __hip_bfloat16 b = __float2bfloat16(f);
  union { __hip_bfloat16 b; unsigned short u; } c; c.b = b; return c.u;
}

// global -> LDS async copy, 16 B per lane; LDS dest = uniform base + lane*16
__device__ __forceinline__ void load_lds16(const void* g, void* l) {
  __builtin_amdgcn_global_load_lds(
      (const __attribute__((address_space(1))) unsigned int*)(unsigned long long)(uintptr_t)g,
      (__attribute__((address_space(3))) unsigned int*)(unsigned int)(uintptr_t)l,
      16, 0, 0);
}

// ---------------------------------------------------------------------------
// h -> bf16
// ---------------------------------------------------------------------------
__global__ void split_h_kernel(const float* __restrict__ h,
                               __hip_bfloat16* __restrict__ Ah) {
  int idx = blockIdx.x * 256 + threadIdx.x;   // exactly N*256 threads
  Ah[idx] = __float2bfloat16(h[idx]);
}

// ---------------------------------------------------------------------------
// Build Bt[768][256] bf16 (B transposed, n-major) + biasP[768] fp32.
// n: 0-255 q, 256-511 k, 512-767 v; channel permuted cc=h*32+d <- c=d*8+h,
// softmax scaling folded into the q group (weights AND bias).
// ---------------------------------------------------------------------------
__global__ void build_bt_kernel(const float* __restrict__ Wq, const float* __restrict__ bq,
                                const float* __restrict__ Wk, const float* __restrict__ bk,
                                const float* __restrict__ Wv, const float* __restrict__ bv,
                                __hip_bfloat16* __restrict__ Bt, float* __restrict__ biasP) {
  const int n  = blockIdx.x;          // 0..767
  const int kk = threadIdx.x;         // 0..255
  const int g  = n >> 8;
  const int cc = n & 255;
  const int c  = ((cc & 31) << 3) + (cc >> 5);     // ref channel d*8+h
  const float scale = (g == 0) ? 0.17677669529663689f : 1.0f;  // HD^-0.5
  const float* W = (g == 0) ? Wq : ((g == 1) ? Wk : Wv);
  Bt[n * 256 + kk] = __float2bfloat16(W[kk * 256 + c] * scale);
  if (kk == 0) {
    const float* b = (g == 0) ? bq : ((g == 1) ? bk : bv);
    biasP[n] = b[c] * scale;
  }
}

// ---------------------------------------------------------------------------
// row_ptr[i] = lower_bound(edge_rows, i); edge_rows is sorted.
// ---------------------------------------------------------------------------
__global__ void build_row_ptr(const int* __restrict__ er, int* __restrict__ rp) {
  int i = blockIdx.x * blockDim.x + threadIdx.x;
  if (i > kN) return;
  int lo = 0, hi = kE;
  while (lo < hi) {
    int mid = (lo + hi) >> 1;
    if (er[mid] < i) lo = mid + 1; else hi = mid;
  }
  rp[i] = lo;
}

// ---------------------------------------------------------------------------
// Fused MFMA GEMM: C[M=50000][768] = A[M][256] * Bt[768][256]^T + bias.
// 128x128 tile, BK=64, 256 threads (4 waves 2x2),
// global_load_lds width-16 staging, XOR-swizzled LDS chunks (conflict-free).
// Epilogue: C tile staged bf16 in LDS (padded), stored as coalesced 16B chunks.
// ---------------------------------------------------------------------------
__global__ __launch_bounds__(256) void gemm_qkv_kernel(
    const __hip_bfloat16* __restrict__ Ah,
    const __hip_bfloat16* __restrict__ Bt, const float* __restrict__ biasP,
    __hip_bfloat16* __restrict__ qb, __hip_bfloat16* __restrict__ kvb) {
  __shared__ __align__(16) char smemRaw[34816];   // max(32 KB tiles, 128*136*2 C)
  short* smemA = (short*)smemRaw;                 // [128][64] 16B-chunk swizzled
  short* smemB = (short*)(smemRaw + 16384);
  short* smemC = (short*)smemRaw;                 // [128][136] padded C tile

  const int tid  = threadIdx.x;
  const int wave = tid >> 6;
  const int lane = tid & 63;
  const int wm = wave & 1;            // M half of tile
  const int wn = wave >> 1;           // N half
  const int colBase = blockIdx.x * 128;   // 6 N-tiles (fast dim -> A reuse in L2)
  const int rowBase = blockIdx.y * 128;   // 391 M-tiles

  f32x4 acc[4][4];
#pragma unroll
  for (int i = 0; i < 4; ++i)
#pragma unroll
    for (int j = 0; j < 4; ++j) acc[i][j] = f32x4{0.f, 0.f, 0.f, 0.f};

  for (int k0 = 0; k0 < 256; k0 += 64) {
    __syncthreads();
    // ---- stage A tile: 128 rows x 64 k (bf16) = 16 KB, 4 calls/wave
#pragma unroll
    for (int j = 0; j < 4; ++j) {
      int s = (wave * 4 + j) * 64 + lane;
      int r = s >> 3, cp = s & 7;
      int c = cp ^ (r & 7);
      int grow = rowBase + r;
      grow = grow < kN ? grow : kN - 1;   // clamp (garbage rows masked at store)
      const char* gp = (const char*)Ah + (size_t)grow * 512 + k0 * 2 + c * 16;
      load_lds16(gp, (char*)smemA + (wave * 4 + j) * 1024);
    }
    // ---- stage B tile: 128 n-rows x 64 k = 16 KB
#pragma unroll
    for (int j = 0; j < 4; ++j) {
      int s = (wave * 4 + j) * 64 + lane;
      int r = s >> 3, cp = s & 7;
      int c = cp ^ (r & 7);
      const char* gp = (const char*)Bt + (size_t)(colBase + r) * 512 + k0 * 2 + c * 16;
      load_lds16(gp, (char*)smemB + (wave * 4 + j) * 1024);
    }
    __syncthreads();

    const int rq = lane & 15, qd = lane >> 4;
#pragma unroll
    for (int ks = 0; ks < 2; ++ks) {
      bf16x8 af[4], bfr[4];
#pragma unroll
      for (int mi = 0; mi < 4; ++mi) {
        int r = wm * 64 + mi * 16 + rq;
        int c = (ks * 4 + qd) ^ (r & 7);
        af[mi] = *(const bf16x8*)&smemA[r * 64 + c * 8];
      }
#pragma unroll
      for (int nj = 0; nj < 4; ++nj) {
        int r = wn * 64 + nj * 16 + rq;
        int c = (ks * 4 + qd) ^ (r & 7);
        bfr[nj] = *(const bf16x8*)&smemB[r * 64 + c * 8];
      }
#pragma unroll
      for (int mi = 0; mi < 4; ++mi)
#pragma unroll
        for (int nj = 0; nj < 4; ++nj)
          acc[mi][nj] = __builtin_amdgcn_mfma_f32_16x16x32_bf16(
              af[mi], bfr[nj], acc[mi][nj], 0, 0, 0);
    }
  }

  // ---- epilogue: stage bf16 C tile in LDS, then coalesced stores.
  // C frag layout: row=(lane>>4)*4+reg, col=lane&15 (verified m89/m91).
  __syncthreads();   // tiles no longer needed; reuse as smemC
#pragma unroll
  for (int nj = 0; nj < 4; ++nj) {
    const int cl = wn * 64 + nj * 16 + (lane & 15);
    const float bb = biasP[colBase + cl];
#pragma unroll
    for (int mi = 0; mi < 4; ++mi) {
      const int rl = wm * 64 + mi * 16 + (lane >> 4) * 4;
#pragma unroll
      for (int reg = 0; reg < 4; ++reg) {
        smemC[(rl + reg) * 136 + cl] = (short)f2bu(acc[mi][nj][reg] + bb);
      }
    }
  }
  __syncthreads();

  const int g = colBase >> 8;   // block-uniform: 0=q 1=k 2=v
#pragma unroll
  for (int it = 0; it < 8; ++it) {
    const int r   = it * 16 + (tid >> 4);      // 0..127
    const int c16 = tid & 15;                  // 16B chunk within row
    const int row = rowBase + r;
    if (row < kN) {
      bf16x8 vls = *(const bf16x8*)&smemC[r * 136 + c16 * 8];
      const int cc = (colBase & 255) + c16 * 8;
      __hip_bfloat16* dst =
          (g == 0) ? (qb + (size_t)row * 256 + cc)
                   : (kvb + (size_t)row * 512 + (g == 2 ? 256 : 0) + cc);
      *(bf16x8*)dst = vls;
    }
  }
}

// ---------------------------------------------------------------------------
// Fused SDDMM + segment softmax + SpMM, no max-subtraction (exact: shift-
// invariant softmax, |score| <= ~1). One wave64 per row, TWO edges per
// iteration: lanes 0-31 edge e, lanes 32-63 edge e+1. Each lane owns 8
// channels (16 B) -> dwordx4 gathers. Head group = 4 lanes (2 shuffles).
// Halves combined at the end via shfl_xor(32); odd tail masked by p=0.
// ---------------------------------------------------------------------------
__global__ __launch_bounds__(256) void edge_attn_kernel(
    const __hip_bfloat16* __restrict__ qb, const __hip_bfloat16* __restrict__ kvb,
    const int* __restrict__ row_ptr, const int* __restrict__ col_ind,
    const float* __restrict__ val, float* __restrict__ out) {
  const int wave = threadIdx.x >> 6;
  const int lane = threadIdx.x & 63;
  const int half = lane >> 5;        // which edge of the pair
  const int sl   = lane & 31;        // channel-group lane (8 ch each)
  const int row = blockIdx.x * 4 + wave;
  if (row >= kN) return;

  const int e0 = row_ptr[row];
  const int e1 = row_ptr[row + 1];

  // q channels sl*8 .. sl*8+7 (same for both halves; broadcast from cache)
  const us8 qu = *(const us8*)(qb + (size_t)row * 256 + sl * 8);
  float qf[8];
#pragma unroll
  for (int j = 0; j < 8; ++j) qf[j] = b2f(qu[j]);

  float denom = 0.f;
  float acc[8];
#pragma unroll
  for (int j = 0; j < 8; ++j) acc[j] = 0.f;

  if (e0 < e1) {
    us8 kA, vA, kB, vB;
    float wA, wB;
    {
      const int eh = min(e0 + half, e1 - 1);
      const int c = col_ind[eh];
      wA = val[eh];
      kA = *(const us8*)(kvb + (size_t)c * 512 + sl * 8);
      vA = *(const us8*)(kvb + (size_t)c * 512 + 256 + sl * 8);
      const int eh2 = min(e0 + 2 + half, e1 - 1);
      const int c2 = col_ind[eh2];
      wB = val[eh2];
      kB = *(const us8*)(kvb + (size_t)c2 * 512 + sl * 8);
      vB = *(const us8*)(kvb + (size_t)c2 * 512 + 256 + sl * 8);
    }

    for (int e = e0; e < e1; e += 2) {
      const us8 kc = kA, vc = vA;
      const float wc = wA;
      kA = kB; vA = vB; wA = wB;
      {
        const int ehN = min(e + 4 + half, e1 - 1);   // branch-free prefetch
        const int c = col_ind[ehN];
        wB = val[ehN];
        kB = *(const us8*)(kvb + (size_t)c * 512 + sl * 8);
        vB = *(const us8*)(kvb + (size_t)c * 512 + 256 + sl * 8);
      }

      float s = 0.f;
#pragma unroll
      for (int j = 0; j < 8; ++j) s = fmaf(qf[j], b2f(kc[j]), s);
      s += __shfl_xor(s, 1);
      s += __shfl_xor(s, 2);     // 4-lane head group reduced
      s *= wc;

      float p = __expf(s);
      p = ((e + half) < e1) ? p : 0.f;   // mask odd-tail duplicate
      denom += p;
#pragma unroll
      for (int j = 0; j < 8; ++j) acc[j] = fmaf(p, b2f(vc[j]), acc[j]);
    }
  }

  // combine the two halves
#pragma unroll
  for (int j = 0; j < 8; ++j) acc[j] += __shfl_xor(acc[j], 32);
  denom += __shfl_xor(denom, 32);

  const float inv = (denom > 0.f) ? (1.0f / denom) : 0.f;
  // lane's channels cc = sl*8 + j live in head h = sl>>2, dim d=(sl&3)*8+j.
  // This lane writes j = half*4 .. half*4+3; ref channel c = d*8 + h.
  const int h = sl >> 2;
  const int dbase = (sl & 3) * 8 + half * 4;
  float* o = out + (size_t)row * 256 + h;
#pragma unroll
  for (int jj = 0; jj < 4; ++jj)
    o[(dbase + jj) * 8] = acc[half * 4 + jj] * inv;
}

// ---------------------------------------------------------------------------
extern "C" void kernel_launch(void* const* d_in, const int* in_sizes, int n_in,
                              void* d_out, int out_size, void* d_ws, size_t ws_size,
                              hipStream_t stream) {
  const float* h   = (const float*)d_in[0];
  const float* val = (const float*)d_in[1];
  const float* Wq  = (const float*)d_in[2];
  const float* bq  = (const float*)d_in[3];
  const float* Wk  = (const float*)d_in[4];
  const float* bk  = (const float*)d_in[5];
  const float* Wv  = (const float*)d_in[6];
  const float* bv  = (const float*)d_in[7];
  const int* edge_rows = (const int*)d_in[8];
  const int* col_ind   = (const int*)d_in[9];
  float* out = (float*)d_out;

  char* ws = (char*)d_ws;
  __hip_bfloat16* Ah  = (__hip_bfloat16*)ws;                 ws += (size_t)kN * 256 * 2;
  __hip_bfloat16* Bt  = (__hip_bfloat16*)ws;                 ws += (size_t)768 * 256 * 2;
  float*          biasP = (float*)ws;                        ws += 768 * 4;
  __hip_bfloat16* qb  = (__hip_bfloat16*)ws;                 ws += (size_t)kN * 256 * 2;
  __hip_bfloat16* kvb = (__hip_bfloat16*)ws;                 ws += (size_t)kN * 512 * 2;
  int* row_ptr = (int*)ws;

  split_h_kernel<<<kN, 256, 0, stream>>>(h, Ah);
  build_bt_kernel<<<768, 256, 0, stream>>>(Wq, bq, Wk, bk, Wv, bv, Bt, biasP);
  build_row_ptr<<<(kN + 1 + 255) / 256, 256, 0, stream>>>(edge_rows, row_ptr);

  gemm_qkv_kernel<<<dim3(6, 391), 256, 0, stream>>>(Ah, Bt, biasP, qb, kvb);

  edge_attn_kernel<<<(kN + 3) / 4, 256, 0, stream>>>(qb, kvb, row_ptr, col_ind,
                                                     val, out);
}

// Round 7
// 291.426 us; speedup vs baseline: 1.0101x; 1.0101x over previous
//
#include <hip/hip_runtime.h>
#include <hip/hip_bf16.h>
#include <math.h>

static constexpr int kN   = 50000;   // nodes
static constexpr int kE   = 800000;  // edges
static constexpr int kHID = 256;
static constexpr int kHD  = 32;

typedef short bf16x8 __attribute__((ext_vector_type(8)));
typedef float f32x4  __attribute__((ext_vector_type(4)));
typedef unsigned short us8 __attribute__((ext_vector_type(8)));

__device__ __forceinline__ float b2f(unsigned short u) {
  union { unsigned v; float f; } c; c.v = ((unsigned)u) << 16; return c.f;
}

__device__ __forceinline__ unsigned short f2bu(float f) {
  __hip_bfloat16 b = __float2bfloat16(f);
  union { __hip_bfloat16 b; unsigned short u; } c; c.b = b; return c.u;
}

// global -> LDS async copy, 16 B per lane; LDS dest = uniform base + lane*16
__device__ __forceinline__ void load_lds16(const void* g, void* l) {
  __builtin_amdgcn_global_load_lds(
      (const __attribute__((address_space(1))) unsigned int*)(unsigned long long)(uintptr_t)g,
      (__attribute__((address_space(3))) unsigned int*)(unsigned int)(uintptr_t)l,
      16, 0, 0);
}

// ---------------------------------------------------------------------------
// h -> bf16
// ---------------------------------------------------------------------------
__global__ void split_h_kernel(const float* __restrict__ h,
                               __hip_bfloat16* __restrict__ Ah) {
  int idx = blockIdx.x * 256 + threadIdx.x;   // exactly N*256 threads
  Ah[idx] = __float2bfloat16(h[idx]);
}

// ---------------------------------------------------------------------------
// Build Bt[768][256] bf16 (B transposed, n-major) + biasP[768] fp32.
// n: 0-255 q, 256-511 k, 512-767 v; channel permuted cc=h*32+d <- c=d*8+h,
// softmax scaling folded into the q group (weights AND bias).
// ---------------------------------------------------------------------------
__global__ void build_bt_kernel(const float* __restrict__ Wq, const float* __restrict__ bq,
                                const float* __restrict__ Wk, const float* __restrict__ bk,
                                const float* __restrict__ Wv, const float* __restrict__ bv,
                                __hip_bfloat16* __restrict__ Bt, float* __restrict__ biasP) {
  const int n  = blockIdx.x;          // 0..767
  const int kk = threadIdx.x;         // 0..255
  const int g  = n >> 8;
  const int cc = n & 255;
  const int c  = ((cc & 31) << 3) + (cc >> 5);     // ref channel d*8+h
  const float scale = (g == 0) ? 0.17677669529663689f : 1.0f;  // HD^-0.5
  const float* W = (g == 0) ? Wq : ((g == 1) ? Wk : Wv);
  Bt[n * 256 + kk] = __float2bfloat16(W[kk * 256 + c] * scale);
  if (kk == 0) {
    const float* b = (g == 0) ? bq : ((g == 1) ? bk : bv);
    biasP[n] = b[c] * scale;
  }
}

// ---------------------------------------------------------------------------
// row_ptr[i] = lower_bound(edge_rows, i); edge_rows is sorted.
// ---------------------------------------------------------------------------
__global__ void build_row_ptr(const int* __restrict__ er, int* __restrict__ rp) {
  int i = blockIdx.x * blockDim.x + threadIdx.x;
  if (i > kN) return;
  int lo = 0, hi = kE;
  while (lo < hi) {
    int mid = (lo + hi) >> 1;
    if (er[mid] < i) lo = mid + 1; else hi = mid;
  }
  rp[i] = lo;
}

// ---------------------------------------------------------------------------
// Fused MFMA GEMM: C[M=50000][768] = A[M][256] * Bt[768][256]^T + bias.
// 128x128 tile, BK=64, 256 threads (4 waves 2x2), global_load_lds staging,
// XOR-swizzled LDS (conflict-free). 1-D grid with XCD-aware decode: all 6
// N-tiles sharing an A-panel land on the SAME XCD consecutively (A in L2).
// Epilogue: C tile staged bf16 in LDS (padded), stored as coalesced 16B chunks.
// ---------------------------------------------------------------------------
__global__ __launch_bounds__(256) void gemm_qkv_kernel(
    const __hip_bfloat16* __restrict__ Ah,
    const __hip_bfloat16* __restrict__ Bt, const float* __restrict__ biasP,
    __hip_bfloat16* __restrict__ qb, __hip_bfloat16* __restrict__ kvb) {
  __shared__ __align__(16) char smemRaw[34816];   // max(32 KB tiles, 128*136*2 C)
  short* smemA = (short*)smemRaw;                 // [128][64] 16B-chunk swizzled
  short* smemB = (short*)(smemRaw + 16384);
  short* smemC = (short*)smemRaw;                 // [128][136] padded C tile

  // XCD-aware decode: L = xcd + 8*(n + 6*mg), m-tile = mg*8 + xcd
  const int L   = blockIdx.x;
  const int xcd = L & 7;
  const int t   = L >> 3;
  const int nt  = t % 6;
  const int mg  = t / 6;
  const int mt  = mg * 8 + xcd;
  if (mt >= 391) return;
  const int colBase = nt * 128;
  const int rowBase = mt * 128;

  const int tid  = threadIdx.x;
  const int wave = tid >> 6;
  const int lane = tid & 63;
  const int wm = wave & 1;            // M half of tile
  const int wn = wave >> 1;           // N half

  f32x4 acc[4][4];
#pragma unroll
  for (int i = 0; i < 4; ++i)
#pragma unroll
    for (int j = 0; j < 4; ++j) acc[i][j] = f32x4{0.f, 0.f, 0.f, 0.f};

  for (int k0 = 0; k0 < 256; k0 += 64) {
    __syncthreads();
    // ---- stage A tile: 128 rows x 64 k (bf16) = 16 KB, 4 calls/wave
#pragma unroll
    for (int j = 0; j < 4; ++j) {
      int s = (wave * 4 + j) * 64 + lane;
      int r = s >> 3, cp = s & 7;
      int c = cp ^ (r & 7);
      int grow = rowBase + r;
      grow = grow < kN ? grow : kN - 1;   // clamp (garbage rows masked at store)
      const char* gp = (const char*)Ah + (size_t)grow * 512 + k0 * 2 + c * 16;
      load_lds16(gp, (char*)smemA + (wave * 4 + j) * 1024);
    }
    // ---- stage B tile: 128 n-rows x 64 k = 16 KB
#pragma unroll
    for (int j = 0; j < 4; ++j) {
      int s = (wave * 4 + j) * 64 + lane;
      int r = s >> 3, cp = s & 7;
      int c = cp ^ (r & 7);
      const char* gp = (const char*)Bt + (size_t)(colBase + r) * 512 + k0 * 2 + c * 16;
      load_lds16(gp, (char*)smemB + (wave * 4 + j) * 1024);
    }
    __syncthreads();

    const int rq = lane & 15, qd = lane >> 4;
#pragma unroll
    for (int ks = 0; ks < 2; ++ks) {
      bf16x8 af[4], bfr[4];
#pragma unroll
      for (int mi = 0; mi < 4; ++mi) {
        int r = wm * 64 + mi * 16 + rq;
        int c = (ks * 4 + qd) ^ (r & 7);
        af[mi] = *(const bf16x8*)&smemA[r * 64 + c * 8];
      }
#pragma unroll
      for (int nj = 0; nj < 4; ++nj) {
        int r = wn * 64 + nj * 16 + rq;
        int c = (ks * 4 + qd) ^ (r & 7);
        bfr[nj] = *(const bf16x8*)&smemB[r * 64 + c * 8];
      }
#pragma unroll
      for (int mi = 0; mi < 4; ++mi)
#pragma unroll
        for (int nj = 0; nj < 4; ++nj)
          acc[mi][nj] = __builtin_amdgcn_mfma_f32_16x16x32_bf16(
              af[mi], bfr[nj], acc[mi][nj], 0, 0, 0);
    }
  }

  // ---- epilogue: stage bf16 C tile in LDS, then coalesced stores.
  // C frag layout: row=(lane>>4)*4+reg, col=lane&15 (verified m89/m91).
  __syncthreads();   // tiles no longer needed; reuse as smemC
#pragma unroll
  for (int nj = 0; nj < 4; ++nj) {
    const int cl = wn * 64 + nj * 16 + (lane & 15);
    const float bb = biasP[colBase + cl];
#pragma unroll
    for (int mi = 0; mi < 4; ++mi) {
      const int rl = wm * 64 + mi * 16 + (lane >> 4) * 4;
#pragma unroll
      for (int reg = 0; reg < 4; ++reg) {
        smemC[(rl + reg) * 136 + cl] = (short)f2bu(acc[mi][nj][reg] + bb);
      }
    }
  }
  __syncthreads();

  const int g = colBase >> 8;   // block-uniform: 0=q 1=k 2=v
#pragma unroll
  for (int it = 0; it < 8; ++it) {
    const int r   = it * 16 + (tid >> 4);      // 0..127
    const int c16 = tid & 15;                  // 16B chunk within row
    const int row = rowBase + r;
    if (row < kN) {
      bf16x8 vls = *(const bf16x8*)&smemC[r * 136 + c16 * 8];
      const int cc = (colBase & 255) + c16 * 8;
      __hip_bfloat16* dst =
          (g == 0) ? (qb + (size_t)row * 256 + cc)
                   : (kvb + (size_t)row * 512 + (g == 2 ? 256 : 0) + cc);
      *(bf16x8*)dst = vls;
    }
  }
}

// ---------------------------------------------------------------------------
// Fused SDDMM + segment softmax + SpMM, no max-subtraction (exact: shift-
// invariant softmax, |score| <= ~1). One wave64 per row, TWO edges per
// iteration (lanes 0-31 / 32-63), 4-stage prefetch pipeline (8 edges in
// flight per wave) to cover ~1000-cycle HBM-class gather latency.
// Lane owns 8 channels (16 B) -> dwordx4 gathers; head group = 4 lanes.
// ---------------------------------------------------------------------------
__global__ __launch_bounds__(256) void edge_attn_kernel(
    const __hip_bfloat16* __restrict__ qb, const __hip_bfloat16* __restrict__ kvb,
    const int* __restrict__ row_ptr, const int* __restrict__ col_ind,
    const float* __restrict__ val, float* __restrict__ out) {
  const int wave = threadIdx.x >> 6;
  const int lane = threadIdx.x & 63;
  const int half = lane >> 5;        // which edge of the pair
  const int sl   = lane & 31;        // channel-group lane (8 ch each)
  const int row = blockIdx.x * 4 + wave;
  if (row >= kN) return;

  const int e0 = row_ptr[row];
  const int e1 = row_ptr[row + 1];

  // q channels sl*8 .. sl*8+7 (same for both halves; broadcast from cache)
  const us8 qu = *(const us8*)(qb + (size_t)row * 256 + sl * 8);
  float qf[8];
#pragma unroll
  for (int j = 0; j < 8; ++j) qf[j] = b2f(qu[j]);

  float denom = 0.f;
  float acc[8];
#pragma unroll
  for (int j = 0; j < 8; ++j) acc[j] = 0.f;

  if (e0 < e1) {
    us8 kS[4], vS[4];          // packed bf16 stages: 4 VGPRs each
    float wS[4];
    const int elast = e1 - 1;
#pragma unroll
    for (int j = 0; j < 4; ++j) {     // warmup: edges e0 + 2j + half
      const int eh = min(e0 + 2 * j + half, elast);
      const int c = col_ind[eh];
      wS[j] = val[eh];
      kS[j] = *(const us8*)(kvb + (size_t)c * 512 + sl * 8);
      vS[j] = *(const us8*)(kvb + (size_t)c * 512 + 256 + sl * 8);
    }

    for (int e = e0; e < e1; e += 8) {   // 4 sub-iters x 2 edges
#pragma unroll
      for (int j = 0; j < 4; ++j) {
        const us8 kc = kS[j], vc = vS[j];
        const float wc = wS[j];
        {
          const int ehN = min(e + 8 + 2 * j + half, elast);   // refill stage j
          const int c = col_ind[ehN];
          wS[j] = val[ehN];
          kS[j] = *(const us8*)(kvb + (size_t)c * 512 + sl * 8);
          vS[j] = *(const us8*)(kvb + (size_t)c * 512 + 256 + sl * 8);
        }

        float s = 0.f;
#pragma unroll
        for (int jj = 0; jj < 8; ++jj) s = fmaf(qf[jj], b2f(kc[jj]), s);
        s += __shfl_xor(s, 1);
        s += __shfl_xor(s, 2);     // 4-lane head group reduced
        s *= wc;

        float p = __expf(s);
        p = ((e + 2 * j + half) < e1) ? p : 0.f;   // mask tail duplicates
        denom += p;
#pragma unroll
        for (int jj = 0; jj < 8; ++jj) acc[jj] = fmaf(p, b2f(vc[jj]), acc[jj]);
      }
    }
  }

  // combine the two halves
#pragma unroll
  for (int j = 0; j < 8; ++j) acc[j] += __shfl_xor(acc[j], 32);
  denom += __shfl_xor(denom, 32);

  const float inv = (denom > 0.f) ? (1.0f / denom) : 0.f;
  // lane's channels cc = sl*8 + j live in head h = sl>>2, dim d=(sl&3)*8+j.
  // This lane writes j = half*4 .. half*4+3; ref channel c = d*8 + h.
  const int h = sl >> 2;
  const int dbase = (sl & 3) * 8 + half * 4;
  float* o = out + (size_t)row * 256 + h;
#pragma unroll
  for (int jj = 0; jj < 4; ++jj)
    o[(dbase + jj) * 8] = acc[half * 4 + jj] * inv;
}

// ---------------------------------------------------------------------------
extern "C" void kernel_launch(void* const* d_in, const int* in_sizes, int n_in,
                              void* d_out, int out_size, void* d_ws, size_t ws_size,
                              hipStream_t stream) {
  const float* h   = (const float*)d_in[0];
  const float* val = (const float*)d_in[1];
  const float* Wq  = (const float*)d_in[2];
  const float* bq  = (const float*)d_in[3];
  const float* Wk  = (const float*)d_in[4];
  const float* bk  = (const float*)d_in[5];
  const float* Wv  = (const float*)d_in[6];
  const float* bv  = (const float*)d_in[7];
  const int* edge_rows = (const int*)d_in[8];
  const int* col_ind   = (const int*)d_in[9];
  float* out = (float*)d_out;

  char* ws = (char*)d_ws;
  __hip_bfloat16* Ah  = (__hip_bfloat16*)ws;                 ws += (size_t)kN * 256 * 2;
  __hip_bfloat16* Bt  = (__hip_bfloat16*)ws;                 ws += (size_t)768 * 256 * 2;
  float*          biasP = (float*)ws;                        ws += 768 * 4;
  __hip_bfloat16* qb  = (__hip_bfloat16*)ws;                 ws += (size_t)kN * 256 * 2;
  __hip_bfloat16* kvb = (__hip_bfloat16*)ws;                 ws += (size_t)kN * 512 * 2;
  int* row_ptr = (int*)ws;

  split_h_kernel<<<kN, 256, 0, stream>>>(h, Ah);
  build_bt_kernel<<<768, 256, 0, stream>>>(Wq, bq, Wk, bk, Wv, bv, Bt, biasP);
  build_row_ptr<<<(kN + 1 + 255) / 256, 256, 0, stream>>>(edge_rows, row_ptr);

  // 391 M-tiles padded to 49 groups of 8; 6 N-tiles; 8 XCD slots
  gemm_qkv_kernel<<<8 * 6 * 49, 256, 0, stream>>>(Ah, Bt, biasP, qb, kvb);

  edge_attn_kernel<<<(kN + 3) / 4, 256, 0, stream>>>(qb, kvb, row_ptr, col_ind,
                                                     val, out);
}